// Round 7
// baseline (277.770 us; speedup 1.0000x reference)
//
#include <hip/hip_runtime.h>
#include <math.h>

// Problem constants
#define BB 8
#define HH 1024
#define WW 1024
#define HW (1024*1024)

#define TW 128          // tile width
#define TH 16           // tile height
#define HALO_H 22       // TH+6
#define TBS 136         // target byte-tile row stride
#define NCHUNK (HALO_H*34)  // 748 int4 chunks of target halo
#define NT 8            // tiles per block (vertical strip of 128 rows)
#define NSLAB (NT*2)    // 8-row slabs
#define NCOPY 64
#define CSTRIDE 64
#define NSLOT 18
// acc layout (copy-major): acc[copy*CSTRIDE + img*NSLOT + slot]

// r0-r6 lesson: duration is invariant (~91us) across occupancy 16-78% and
// staging schemes, and warm replays (1 MB HBM) take the SAME time -> the
// limiter is the per-block fetch -> vmcnt(0)-drain -> compute serialization,
// x4096 blocks. Fix = T3+T4: multi-tile blocks, double-buffered DMA,
// counted vmcnt(3) waits (never 0 in loop), raw s_barrier (syncthreads
// would force a full drain and defeat the pipeline).
typedef const __attribute__((address_space(1))) unsigned GU;
typedef __attribute__((address_space(3))) unsigned LU;
__device__ __forceinline__ void async16(const float* g, const void* lds) {
    __builtin_amdgcn_global_load_lds((GU*)g, (LU*)lds, 16, 0, 0);
}
__device__ __forceinline__ void wait_vm3() {
    asm volatile("s_waitcnt vmcnt(3)" ::: "memory");
    __builtin_amdgcn_sched_barrier(0);
}
__device__ __forceinline__ void wait_vm0() {
    asm volatile("s_waitcnt vmcnt(0)" ::: "memory");
    __builtin_amdgcn_sched_barrier(0);
}
__device__ __forceinline__ void lds_barrier() {   // publish LDS writes + align
    asm volatile("s_waitcnt lgkmcnt(0)" ::: "memory");
    __builtin_amdgcn_s_barrier();
    __builtin_amdgcn_sched_barrier(0);
}
__device__ __forceinline__ void plain_barrier() { // align only; DMA may fly across
    __builtin_amdgcn_s_barrier();
    __builtin_amdgcn_sched_barrier(0);
}

__global__ __launch_bounds__(512, 4)
void loss_main(const float* __restrict__ pred,
               const float* __restrict__ diss,
               const int*   __restrict__ target,
               double*      __restrict__ acc)
{
    // LDS: 49152 + 5984 + 5120 + 4096 + 384 = 64736 B -> 2 blocks/CU.
    __shared__ __align__(16) float pbuf[2][6][8][128];           // slab ring
    __shared__ __align__(16) unsigned char tb[2][HALO_H][TBS];   // packed target
    __shared__ __align__(16) unsigned char h5b[2][20][128];      // 5-wide sums (rows 1..20)
    __shared__ __align__(16) unsigned char h7b[2][16][128];      // 7-wide sums (rows 3..18)
    __shared__ float red[8][12];

    const int bx  = blockIdx.x;      // 0..7 column strip
    const int bys = blockIdx.y;      // 0..7 row strip (128 rows)
    const int b   = blockIdx.z;      // 0..7
    const int x0 = bx * TW;
    const int ys = bys * 128;
    const int tid = threadIdx.x;     // 0..511
    const int w  = tid >> 6;         // wave 0..7 (= row within slab for C)
    const int ln = tid & 63;

    const int* tgt_b = target + (size_t)b * HW;

    // ---- plane DMA: 24 chunks of 1KB per slab, 3 per wave ----
    auto issueP = [&](int sn) {
        const int Xn  = sn & 1;
        const int gy0 = ys + (sn >> 1) * 16 + (sn & 1) * 8;
        #pragma unroll
        for (int k = 0; k < 3; ++k) {
            const int c  = w + 8 * k;            // 0..23
            const int pl = c >> 2, rp = c & 3;
            const float* base = (pl < 4)
                ? (pred + (size_t)((pl >> 1) * 16 + b * 2 + (pl & 1)) * HW)
                : (diss + (size_t)(b * 2 + (pl & 1)) * HW);
            const int gy = gy0 + 2 * rp + (ln >> 5);
            const int gx = x0 + (ln & 31) * 4;
            async16(base + (size_t)gy * WW + gx, &pbuf[Xn][pl][2 * rp][0]);
        }
    };

    // ---- target halo loads (issued BEFORE P so pack's implicit wait is
    //      vmcnt(3), retiring slab-s planes while slab-s+1 stays in flight).
    //      Note: the 4-px x-halo is exactly one aligned int4, so partial
    //      words never occur -> branchless select, no fallback loads.
    int4 iv0, iv1;
    int rr0, mm0, rr1, mm1;
    bool ok0, ok1, act1;
    auto issueT = [&](int tn) {
        const int ty0 = ys + tn * 16 - 3;
        {
            const int r = tid / 34, m = tid - r * 34;
            const int gy = ty0 + r;
            const int gxb = x0 - 4 + 4 * m;
            const bool rin = (gy >= 0) && (gy < HH);
            const bool xin = (gxb >= 0) && (gxb + 3 < WW);
            rr0 = r; mm0 = m; ok0 = rin && xin;
            iv0 = *(const int4*)(tgt_b + (size_t)(rin ? gy : 0) * WW + (xin ? gxb : 0));
        }
        act1 = (tid + 512) < NCHUNK;
        {
            const int ch = act1 ? (tid + 512) : 0;
            const int r = ch / 34, m = ch - r * 34;
            const int gy = ty0 + r;
            const int gxb = x0 - 4 + 4 * m;
            const bool rin = (gy >= 0) && (gy < HH);
            const bool xin = (gxb >= 0) && (gxb + 3 < WW);
            rr1 = r; mm1 = m; ok1 = act1 && rin && xin;
            if (act1)
                iv1 = *(const int4*)(tgt_b + (size_t)(rin ? gy : 0) * WW + (xin ? gxb : 0));
        }
    };
    auto packT = [&](int tn) {
        const int Y = tn & 1;
        unsigned v0 = ok0 ? ((unsigned)(iv0.x & 0xff)
                           | ((unsigned)(iv0.y & 0xff) << 8)
                           | ((unsigned)(iv0.z & 0xff) << 16)
                           | ((unsigned)(iv0.w & 0xff) << 24)) : 0u;
        *(unsigned*)&tb[Y][rr0][4 * mm0] = v0;
        if (act1) {
            unsigned v1 = ok1 ? ((unsigned)(iv1.x & 0xff)
                               | ((unsigned)(iv1.y & 0xff) << 8)
                               | ((unsigned)(iv1.z & 0xff) << 16)
                               | ((unsigned)(iv1.w & 0xff) << 24)) : 0u;
            *(unsigned*)&tb[Y][rr1][4 * mm1] = v1;
        }
    };

    // ---- horizontal SWAR sums (704 word-groups) ----
    auto doH = [&](int tn) {
        const int Y = tn & 1;
        #pragma unroll
        for (int i = 0; i < 2; ++i) {
            const int g = tid + 512 * i;
            if (g >= HALO_H * 32) break;
            const int r = g >> 5, xg = (g & 31) << 2;
            unsigned c0 = *(const unsigned*)&tb[Y][r][xg];
            unsigned c1 = *(const unsigned*)&tb[Y][r][xg + 4];
            unsigned c2 = *(const unsigned*)&tb[Y][r][xg + 8];
            unsigned A1 = (c0 >> 8)  | (c1 << 24);
            unsigned A2 = (c0 >> 16) | (c1 << 16);
            unsigned A3 = (c0 >> 24) | (c1 << 8);
            unsigned A5 = (c1 >> 8)  | (c2 << 24);
            unsigned A6 = (c1 >> 16) | (c2 << 16);
            unsigned A7 = (c1 >> 24) | (c2 << 8);
            unsigned v5 = A2 + A3 + c1 + A5 + A6;   // bytes <= 5
            unsigned v7 = v5 + A1 + A7;             // bytes <= 7
            if (r >= 1 && r <= 20) *(unsigned*)&h5b[Y][r - 1][xg] = v5;
            if (r >= 3 && r <= 18) *(unsigned*)&h7b[Y][r - 3][xg] = v7;
        }
    };

    // ---- per-slab compute: 1 row/wave, 2 px/thread, accumulate in regs ----
    float sf0=0.f, se0=0.f, si0=0.f, sp0=0.f;
    float sf1=0.f, se1=0.f, si1=0.f, sp1=0.f;
    float sf2=0.f, se2=0.f, si2=0.f, sd1=0.f;
    float st = 0.f;

    auto doC = [&](int s) {
        const int t = s >> 1, p = s & 1, X = t & 1, PB = s & 1;
        const int tr = p * 8 + w;        // tile row 0..15
        const int hr = tr + 3;           // halo row 3..18
        const int wb5 = (2 * ln) & ~3;   // h5/h7 word byte offset
        const int wbt = wb5 + 4;         // tb word (stored col = px col + 4)
        const int sh = (ln & 1) * 16;
        const unsigned t4w = *(const unsigned*)&tb[X][hr][wbt];
        const unsigned cw  = *(const unsigned*)&tb[X][tr][wbt]
                           + *(const unsigned*)&tb[X][tr + 6][wbt]
                           + *(const unsigned*)&h5b[X][hr - 3][wb5]
                           + *(const unsigned*)&h5b[X][hr - 2][wb5]
                           + *(const unsigned*)&h5b[X][hr    ][wb5]
                           + *(const unsigned*)&h5b[X][hr + 1][wb5]
                           + *(const unsigned*)&h7b[X][hr - 3][wb5];
        const float2 f00 = *(const float2*)&pbuf[PB][0][w][2 * ln];
        const float2 f01 = *(const float2*)&pbuf[PB][1][w][2 * ln];
        const float2 f10 = *(const float2*)&pbuf[PB][2][w][2 * ln];
        const float2 f11 = *(const float2*)&pbuf[PB][3][w][2 * ln];
        const float2 g0  = *(const float2*)&pbuf[PB][4][w][2 * ln];
        const float2 g1  = *(const float2*)&pbuf[PB][5][w][2 * ln];
        #pragma unroll
        for (int j = 0; j < 2; ++j) {
            const unsigned tv = (t4w >> (sh + 8 * j)) & 0xffu;
            const float tf = (float)tv;
            const float at = fabsf(tf - (float)((cw >> (sh + 8 * j)) & 0xffu) * (1.0f / 29.0f));
            st += tf;
            {   // image 0 (softmax of 2 channels)
                float a0 = ((const float*)&f00)[j], a1 = ((const float*)&f01)[j];
                float p1v = __builtin_amdgcn_rcpf(1.0f + __expf(a0 - a1));
                float pt  = (tv != 0u) ? p1v : 1.0f - p1v;
                float lp  = __logf(pt + 1e-10f);
                sf0 -= lp; se0 -= lp * at; si0 += p1v * tf; sp0 += p1v;
            }
            {   // image 1
                float a0 = ((const float*)&f10)[j], a1 = ((const float*)&f11)[j];
                float p1v = __builtin_amdgcn_rcpf(1.0f + __expf(a0 - a1));
                float pt  = (tv != 0u) ? p1v : 1.0f - p1v;
                float lp  = __logf(pt + 1e-10f);
                sf1 -= lp; se1 -= lp * at; si1 += p1v * tf; sp1 += p1v;
            }
            {   // Diss (raw probs)
                float d0 = ((const float*)&g0)[j], d1 = ((const float*)&g1)[j];
                float pt = (tv != 0u) ? d1 : d0;
                float lp = __logf(pt + 1e-10f);
                sf2 -= lp; se2 -= lp * at; si2 += d1 * tf; sd1 += d1;
            }
        }
    };

    // ---- prologue: tile 0 target + slab 0 planes ----
    __builtin_amdgcn_sched_barrier(0);
    issueT(0);
    __builtin_amdgcn_sched_barrier(0);
    issueP(0);
    __builtin_amdgcn_sched_barrier(0);
    packT(0);             // implicit vmcnt(3): T done, P(0) stays in flight
    lds_barrier();        // tb[0] visible
    doH(0);               // h5b[0]/h7b[0] (published by slab 0's lds_barrier)

    // ---- main pipeline: 16 slabs, counted waits, 2 barriers/slab ----
    for (int s = 0; s < NSLAB; ++s) {
        plain_barrier();                 // buffers (s+1)&1 now free to overwrite
        const int t = s >> 1;
        if ((s & 1) == 0) {
            if (t + 1 < NT) {
                __builtin_amdgcn_sched_barrier(0);
                issueT(t + 1);
                __builtin_amdgcn_sched_barrier(0);
                issueP(s + 1);
                __builtin_amdgcn_sched_barrier(0);
                packT(t + 1);            // implicit vmcnt(3): retires P(s)+T
                wait_vm3();              // belt-and-suspenders: P(s) done
            } else {                     // s == 14
                issueP(s + 1);
                wait_vm3();
            }
        } else {
            if (s + 1 < NSLAB) {
                issueP(s + 1);
                doH(t + 1);              // LDS-only; overlaps DMA flight
                wait_vm3();              // P(s) done, P(s+1) in flight
            } else {
                wait_vm0();              // last slab: drain
            }
        }
        lds_barrier();                   // publish tb/h sums; all waves past vm-wait
        doC(s);
    }

    // ---- epilogue: one reduction + 12 atomics per block ----
    float vals[12] = {sf0,se0,si0,sp0+st, sf1,se1,si1,sp1+st, sf2,se2,si2,sd1+st};
    #pragma unroll
    for (int j = 0; j < 12; ++j) {
        float v = vals[j];
        #pragma unroll
        for (int sft = 32; sft > 0; sft >>= 1) v += __shfl_down(v, sft, 64);
        vals[j] = v;
    }
    if (ln == 0) {
        #pragma unroll
        for (int j = 0; j < 12; ++j) red[w][j] = vals[j];
    }
    __syncthreads();
    if (tid < 12) {
        double sacc = 0.0;
        #pragma unroll
        for (int k = 0; k < 8; ++k) sacc += (double)red[k][tid];
        const int img  = tid >> 2;
        const int what = tid & 3;
        int slot;
        if      (what == 0) slot = 0;
        else if (what == 1) slot = 1;
        else if (what == 2) slot = 2 + b;
        else                slot = 10 + b;
        const int copy = (bys * 8 + bx) & (NCOPY - 1);
        unsafeAtomicAdd(acc + (size_t)copy * CSTRIDE + (img * NSLOT + slot), sacc);
    }
}

__global__ __launch_bounds__(256)
void finalize_kernel(const double* __restrict__ acc,
                     const float*  __restrict__ diff,
                     const float*  __restrict__ sigma,
                     float*        __restrict__ out)
{
    __shared__ double ssum[54];
    const int t = threadIdx.x;
    if (t < 216) {
        const int slot_lin = t >> 2;
        const int part     = t & 3;
        const double* p = acc + slot_lin + (size_t)part * 16 * CSTRIDE;
        double s = 0.0;
        #pragma unroll
        for (int j = 0; j < 16; ++j) s += p[(size_t)j * CSTRIDE];
        s += __shfl_down(s, 1, 64);
        s += __shfl_down(s, 2, 64);
        if (part == 0) ssum[slot_lin] = s;
    }
    __syncthreads();
    if (t == 0) {
        const double sig0 = (double)sigma[0] * (double)sigma[0];
        const double sig1 = (double)sigma[1] * (double)sigma[1];
        const double sig2 = (double)sigma[2] * (double)sigma[2];
        const double inv  = 1.0 / (double)((size_t)BB * HW);
        double loss = 0.0;
        for (int i = 0; i < 3; ++i) {
            const double* A = ssum + i * NSLOT;
            double focal = A[0] * inv;
            double edge  = A[1] * inv;
            double dsum  = 0.0;
            for (int b = 0; b < BB; ++b)
                dsum += 2.0 * A[2 + b] / (A[10 + b] + 1e-10);
            double dice = 1.0 - dsum / (double)BB;
            loss += focal / sig0 + dice / sig1 + edge / sig2;
        }
        loss += (double)diff[0];
        loss += 0.5 * (log(sig0) + log(sig1) + log(sig2));
        out[0] = (float)loss;
    }
}

extern "C" void kernel_launch(void* const* d_in, const int* in_sizes, int n_in,
                              void* d_out, int out_size, void* d_ws, size_t ws_size,
                              hipStream_t stream)
{
    const float* pred   = (const float*)d_in[0]; // (2,8,2,1024,1024)
    const float* diss   = (const float*)d_in[1]; // (1,8,2,1024,1024)
    const int*   target = (const int*)  d_in[2]; // (8,1024,1024)
    const float* diff   = (const float*)d_in[3];
    const float* sigma  = (const float*)d_in[4];
    double* acc = (double*)d_ws;

    (void)hipMemsetAsync(d_ws, 0, (size_t)NCOPY * CSTRIDE * sizeof(double), stream);

    dim3 grid(WW / TW, HH / 128, BB);   // (8, 8, 8) = 512 blocks, 8 tiles each
    loss_main<<<grid, 512, 0, stream>>>(pred, diss, target, acc);
    finalize_kernel<<<1, 256, 0, stream>>>(acc, diff, sigma, (float*)d_out);
}